// Round 12
// baseline (352.134 us; speedup 1.0000x reference)
//
#include <hip/hip_runtime.h>
#include <hip/hip_bf16.h>

static constexpr int HEADS = 8;
static constexpr int D1 = 256;      // HEADS*HID
static constexpr int ODIM = 64;
static constexpr float NEG = 0.2f;

typedef __attribute__((ext_vector_type(8))) short bf16x8;
typedef __attribute__((ext_vector_type(8))) unsigned short u16x8;
typedef __attribute__((ext_vector_type(4))) float f32x4;

__device__ __forceinline__ float lrelu(float x) { return fmaxf(x, NEG * x); }
__device__ __forceinline__ float elu1(float x) { return x > 0.f ? x : expm1f(x); }

__device__ __forceinline__ unsigned short f2bf(float f) {
  unsigned u = __float_as_uint(f);
  unsigned r = (u + 0x7fffu + ((u >> 16) & 1u)) >> 16;
  return (unsigned short)r;
}
__device__ __forceinline__ float bf2f(unsigned short h) {
  return __uint_as_float((unsigned)h << 16);
}

__device__ __forceinline__ void gload_lds16(const void* g, void* l) {
  __builtin_amdgcn_global_load_lds(
      (const __attribute__((address_space(1))) void*)g,
      (__attribute__((address_space(3))) void*)l, 16, 0, 0);
}

// physical XCD id (HW_REG_XCC_ID = 20 on gfx94x/950). Value only steers
// scheduling; correctness never depends on it (work-steal loop below).
__device__ __forceinline__ int xcd_id() {
  int x;
  asm volatile("s_getreg_b32 %0, hwreg(20, 0, 32)" : "=s"(x));
  return x & 7;
}

// ---------------- hist (rank-capturing) + weight-prep (merged) ----------------
__global__ void k_hist_prep(const int* __restrict__ dst, int E, int TE,
                            int* __restrict__ deg, int* __restrict__ erank,
                            const float* __restrict__ W1, const float* __restrict__ W2,
                            unsigned short* __restrict__ BT1, unsigned short* __restrict__ B2T,
                            int HB) {
  int b = blockIdx.x;
  if (b < HB) {
    int i = b * 256 + threadIdx.x;
    if (i < TE) {
      int d = (i < E) ? __builtin_nontemporal_load(&dst[i]) : (i - E);
      int rk = atomicAdd(&deg[d], 1);   // rank within segment, fixes scatter order
      __builtin_nontemporal_store(rk, &erank[i]);
    }
  } else {
    int t = (b - HB) * 256 + threadIdx.x;
    if (t < 65536) {
      int k = t >> 8, nn = t & 255;
      BT1[nn * 256 + k] = f2bf(W1[t]);
    } else if (t < 65536 + 16384) {
      int t2 = t - 65536;
      int k = t2 >> 6, nn = t2 & 63;
      B2T[nn * 256 + k] = f2bf(W2[t2]);
    }
  }
}

// ---------------- single-launch exclusive scan (decoupled lookback) ----------------
__global__ void k_scan_lb(const int* __restrict__ deg, int n, int TE,
                          int* __restrict__ offs,
                          int* __restrict__ tstate, int* __restrict__ ticket) {
  __shared__ int sm[256];
  __shared__ int sh[2];
  if (threadIdx.x == 0) sh[0] = atomicAdd(ticket, 1);
  __syncthreads();
  const int tile = sh[0];
  int i = tile * 256 + threadIdx.x;
  int v = (i < n) ? deg[i] : 0;
  sm[threadIdx.x] = v;
  __syncthreads();
  for (int off = 1; off < 256; off <<= 1) {
    int t = (threadIdx.x >= off) ? sm[threadIdx.x - off] : 0;
    __syncthreads();
    sm[threadIdx.x] += t;
    __syncthreads();
  }
  const int total = sm[255];
  if (threadIdx.x == 0) {
    if (tile == 0) {
      __hip_atomic_store(&tstate[0], (2 << 24) | total, __ATOMIC_RELEASE,
                         __HIP_MEMORY_SCOPE_AGENT);
      sh[1] = 0;
    } else {
      __hip_atomic_store(&tstate[tile], (1 << 24) | total, __ATOMIC_RELEASE,
                         __HIP_MEMORY_SCOPE_AGENT);
    }
  }
  __syncthreads();
  if (tile != 0) {
    if (threadIdx.x < 64) {
      const int lane = threadIdx.x;
      int running = 0;
      int wstart = tile - 1;
      for (;;) {
        int idx = wstart - lane;
        int st = (idx >= 0)
                     ? __hip_atomic_load(&tstate[idx], __ATOMIC_ACQUIRE,
                                         __HIP_MEMORY_SCOPE_AGENT)
                     : (2 << 24);
        if (__ballot(st == 0)) continue;
        unsigned long long pref = __ballot((st >> 24) == 2);
        int contrib;
        if (pref) {
          int flane = (int)__ffsll(pref) - 1;
          contrib = (lane <= flane) ? (st & 0xFFFFFF) : 0;
        } else {
          contrib = st & 0xFFFFFF;
        }
#pragma unroll
        for (int off2 = 1; off2 < 64; off2 <<= 1) contrib += __shfl_xor(contrib, off2);
        running += contrib;
        if (pref) break;
        wstart -= 64;
      }
      if (lane == 0) {
        sh[1] = running;
        __hip_atomic_store(&tstate[tile], (2 << 24) | (running + total),
                           __ATOMIC_RELEASE, __HIP_MEMORY_SCOPE_AGENT);
      }
    }
    __syncthreads();
  }
  const int base = sh[1];
  if (i < n) offs[i] = base + sm[threadIdx.x] - v;
  if (i == 0) offs[n] = TE;
}

// ---------------- GEMM1 (1-term bf16, BN=256, x-prefetch) + fused alpha1 ∥ NT scatter ----
__global__ __launch_bounds__(512) void k_gemm1s(
    const float* __restrict__ X,
    const unsigned short* __restrict__ BT,
    const float* __restrict__ a_src, const float* __restrict__ a_dst,
    unsigned short* __restrict__ h1b,
    float* __restrict__ asrc, float* __restrict__ adst,
    int M, int Mblk,
    const int* __restrict__ src, const int* __restrict__ dst, int E, int TE,
    const int* __restrict__ offs, const int* __restrict__ erank,
    int* __restrict__ csr_src) {
  __shared__ __align__(128) char As[16384];
  __shared__ __align__(128) char Bs[32768];
  if (blockIdx.x >= Mblk) {
    int i = (blockIdx.x - Mblk) * 512 + threadIdx.x;
    if (i < TE) {
      int s, d;
      if (i < E) {
        s = __builtin_nontemporal_load(&src[i]);
        d = __builtin_nontemporal_load(&dst[i]);
      } else { s = i - E; d = i - E; }
      int rk = __builtin_nontemporal_load(&erank[i]);
      __builtin_nontemporal_store(s, &csr_src[offs[d] + rk]);
    }
    return;
  }
  const int tid = threadIdx.x;
  const int lane = tid & 63;
  const int wid = tid >> 6;
  const int bm = blockIdx.x * 128;
  const int wm = wid >> 2, wn = wid & 3;
  f32x4 acc[4][4] = {};
  float4 xv[2][2];
  auto loadX = [&](int kb) {
#pragma unroll
    for (int q = 0; q < 2; ++q) {
      int c = q * 512 + tid;
      int r = c >> 3, kc = c & 7;
      int gr = bm + r;
      xv[q][0] = make_float4(0.f, 0.f, 0.f, 0.f);
      xv[q][1] = xv[q][0];
      if (gr < M) {
        xv[q][0] = *(const float4*)&X[(size_t)gr * 256 + kb + kc * 8];
        xv[q][1] = *(const float4*)&X[(size_t)gr * 256 + kb + kc * 8 + 4];
      }
    }
  };
  loadX(0);
  for (int kb = 0; kb < 256; kb += 64) {
#pragma unroll
    for (int q = 0; q < 2; ++q) {
      int c = q * 512 + tid;
      int r = c >> 3, kc = c & 7;
      float vv[8] = {xv[q][0].x, xv[q][0].y, xv[q][0].z, xv[q][0].w,
                     xv[q][1].x, xv[q][1].y, xv[q][1].z, xv[q][1].w};
      u16x8 hv;
#pragma unroll
      for (int j = 0; j < 8; ++j) hv[j] = f2bf(vv[j]);
      *(u16x8*)(As + r * 128 + ((kc * 16) ^ ((r & 7) << 4))) = hv;
    }
#pragma unroll
    for (int q = 0; q < 4; ++q) {
      int c = q * 512 + tid;
      int col = c >> 3;
      int b = ((c & 7) * 16) ^ ((col & 7) << 4);
      gload_lds16(BT + (size_t)col * 256 + kb + (b >> 1),
                  Bs + (size_t)(q * 512 + (tid & ~63)) * 16);
    }
    __syncthreads();
    if (kb + 64 < 256) loadX(kb + 64);
#pragma unroll
    for (int ks = 0; ks < 2; ++ks) {
      bf16x8 af[4], bfr[4];
      int bb = ks * 64 + (lane >> 4) * 16;
#pragma unroll
      for (int mi = 0; mi < 4; ++mi) {
        int row = wm * 64 + mi * 16 + (lane & 15);
        af[mi] = *(const bf16x8*)(As + row * 128 + (bb ^ ((row & 7) << 4)));
      }
#pragma unroll
      for (int ni = 0; ni < 4; ++ni) {
        int col = wn * 64 + ni * 16 + (lane & 15);
        bfr[ni] = *(const bf16x8*)(Bs + col * 128 + (bb ^ ((col & 7) << 4)));
      }
#pragma unroll
      for (int mi = 0; mi < 4; ++mi)
#pragma unroll
        for (int ni = 0; ni < 4; ++ni)
          acc[mi][ni] = __builtin_amdgcn_mfma_f32_16x16x32_bf16(af[mi], bfr[ni],
                                                                acc[mi][ni], 0, 0, 0);
    }
    __syncthreads();
  }
  const int h0 = 2 * wn, h1h = 2 * wn + 1;
  const int cl = lane & 15;
  const float as0 = a_src[h0 * 32 + cl],      ad0 = a_dst[h0 * 32 + cl];
  const float as1 = a_src[h0 * 32 + 16 + cl], ad1 = a_dst[h0 * 32 + 16 + cl];
  const float as2 = a_src[h1h * 32 + cl],      ad2 = a_dst[h1h * 32 + cl];
  const float as3 = a_src[h1h * 32 + 16 + cl], ad3 = a_dst[h1h * 32 + 16 + cl];
#pragma unroll
  for (int mi = 0; mi < 4; ++mi) {
    int gr0 = bm + wm * 64 + mi * 16 + (lane >> 4) * 4;
#pragma unroll
    for (int j = 0; j < 4; ++j) {
      int gr = gr0 + j;
#pragma unroll
      for (int ni = 0; ni < 4; ++ni) {
        int gc = wn * 64 + ni * 16 + cl;
        if (gr < M) h1b[(size_t)gr * 256 + gc] = f2bf(acc[mi][ni][j]);
      }
      float ps0 = acc[mi][0][j] * as0 + acc[mi][1][j] * as1;
      float pd0 = acc[mi][0][j] * ad0 + acc[mi][1][j] * ad1;
      float ps1 = acc[mi][2][j] * as2 + acc[mi][3][j] * as3;
      float pd1 = acc[mi][2][j] * ad2 + acc[mi][3][j] * ad3;
#pragma unroll
      for (int off = 1; off < 16; off <<= 1) {
        ps0 += __shfl_xor(ps0, off);
        pd0 += __shfl_xor(pd0, off);
        ps1 += __shfl_xor(ps1, off);
        pd1 += __shfl_xor(pd1, off);
      }
      if (cl == 0 && gr < M) {
        asrc[gr * 8 + h0] = ps0;
        adst[gr * 8 + h0] = pd0;
        asrc[gr * 8 + h1h] = ps1;
        adst[gr * 8 + h1h] = pd1;
      }
    }
  }
}

// ---------------- layer-1 aggregation: XCD-sliced by head ----------------
// Block claims a (slice=head, 64-node chunk) with slice preferring its own
// XCD, so each XCD's L2 caches only its 3.2 MB head-slice of h1b.
// Wave: 16 edge slots x 4 lanes (u16x8 = the slice's 32 channels).
__global__ __launch_bounds__(256) void k_agg1(
    const int* __restrict__ offs, const int* __restrict__ csr_src,
    const unsigned short* __restrict__ h1b, const float* __restrict__ asrc,
    const float* __restrict__ adst, const float* __restrict__ b1,
    int n, int cps, int* __restrict__ sticket,
    unsigned short* __restrict__ helu) {
  __shared__ int sh_chunk, sh_slice;
  if (threadIdx.x == 0) {
    int sl = xcd_id();
    int got = -1, gsl = 0;
    for (int o = 0; o < 8; ++o) {
      int s2 = (sl + o) & 7;
      int t = atomicAdd(&sticket[s2], 1);
      if (t < cps) { got = t; gsl = s2; break; }
    }
    sh_chunk = got;
    sh_slice = gsl;
  }
  __syncthreads();
  const int chunk = sh_chunk;
  const int h = sh_slice;              // head = channel slice
  if (chunk < 0) return;
  const int lane = threadIdx.x & 63;
  const int wid = threadIdx.x >> 6;
  const int es = lane >> 2;            // edge slot 0..15
  const int cq = lane & 3;             // channel quad (8 ch)
  const int cb = h * 32 + cq * 8;      // channel base
  float4 bbv0 = *(const float4*)&b1[cb];
  float4 bbv1 = *(const float4*)&b1[cb + 4];
  float bb[8] = {bbv0.x, bbv0.y, bbv0.z, bbv0.w, bbv1.x, bbv1.y, bbv1.z, bbv1.w};
  for (int t = 0; t < 16; ++t) {
    const int node = chunk * 64 + wid * 16 + t;
    if (node >= n) break;
    const int b = offs[node], e2 = offs[node + 1];
    const float ad = adst[node * 8 + h];
    float ssum = 0.f;
    float acc[8] = {};
    int i = b;
    for (; i + 15 < e2; i += 16) {
      int s = csr_src[i + es];
      u16x8 r = *(const u16x8*)&h1b[(size_t)s * D1 + cb];
      float w = __expf(lrelu(asrc[s * 8 + h] + ad));
      ssum += w;
#pragma unroll
      for (int j = 0; j < 8; ++j) acc[j] += w * bf2f(r[j]);
    }
    if (i < e2) {
      int idx = i + es;
      bool act = idx < e2;
      int s = csr_src[act ? idx : e2 - 1];
      u16x8 r = *(const u16x8*)&h1b[(size_t)s * D1 + cb];
      float w = act ? __expf(lrelu(asrc[s * 8 + h] + ad)) : 0.f;
      ssum += w;
#pragma unroll
      for (int j = 0; j < 8; ++j) acc[j] += w * bf2f(r[j]);
    }
#pragma unroll
    for (int off = 4; off < 64; off <<= 1) {
      ssum += __shfl_xor(ssum, off);
#pragma unroll
      for (int j = 0; j < 8; ++j) acc[j] += __shfl_xor(acc[j], off);
    }
    if (es == 0) {
      float rr = 1.f / ssum;
      u16x8 o;
#pragma unroll
      for (int j = 0; j < 8; ++j) o[j] = f2bf(elu1(acc[j] * rr + bb[j]));
      *(u16x8*)&helu[(size_t)node * D1 + cb] = o;
    }
  }
}

// ---------------- GEMM2 (1-term bf16, K=256) + fused alpha2 ----------------
__global__ __launch_bounds__(512) void k_gemm2(
    const unsigned short* __restrict__ A,    // helu [Mpad][256] bf16
    const unsigned short* __restrict__ B2T,  // [64][256] (hi)
    const float* __restrict__ a_src, const float* __restrict__ a_dst,
    unsigned short* __restrict__ C,          // h2b [M][64]
    float* __restrict__ asrc, float* __restrict__ adst,
    int M) {
  __shared__ __align__(128) char As[16384];
  __shared__ __align__(128) char Bs[8192];
  __shared__ float red[2][128][2];
  const int tid = threadIdx.x;
  const int lane = tid & 63;
  const int wid = tid >> 6;
  const int bm = blockIdx.x * 128;
  const int wm = wid >> 1, wn = wid & 1;
  f32x4 acc[2][2] = {};
  for (int kb = 0; kb < 256; kb += 64) {
#pragma unroll
    for (int q = 0; q < 2; ++q) {
      int c = q * 512 + tid;
      int r = c >> 3;
      int b = ((c & 7) * 16) ^ ((r & 7) << 4);
      gload_lds16(A + (size_t)(bm + r) * 256 + kb + (b >> 1),
                  As + (size_t)(q * 512 + (tid & ~63)) * 16);
    }
    {
      int c = tid;
      int col = c >> 3;
      int b = ((c & 7) * 16) ^ ((col & 7) << 4);
      gload_lds16(B2T + (size_t)col * 256 + kb + (b >> 1),
                  Bs + (size_t)(tid & ~63) * 16);
    }
    __syncthreads();
#pragma unroll
    for (int ks = 0; ks < 2; ++ks) {
      bf16x8 af[2], bfr[2];
      int bb = ks * 64 + (lane >> 4) * 16;
#pragma unroll
      for (int mi = 0; mi < 2; ++mi) {
        int row = wm * 32 + mi * 16 + (lane & 15);
        af[mi] = *(const bf16x8*)(As + row * 128 + (bb ^ ((row & 7) << 4)));
      }
#pragma unroll
      for (int ni = 0; ni < 2; ++ni) {
        int col = wn * 32 + ni * 16 + (lane & 15);
        bfr[ni] = *(const bf16x8*)(Bs + col * 128 + (bb ^ ((col & 7) << 4)));
      }
#pragma unroll
      for (int mi = 0; mi < 2; ++mi)
#pragma unroll
        for (int ni = 0; ni < 2; ++ni)
          acc[mi][ni] = __builtin_amdgcn_mfma_f32_16x16x32_bf16(af[mi], bfr[ni],
                                                                acc[mi][ni], 0, 0, 0);
    }
    __syncthreads();
  }
  const int cl = lane & 15;
  const float a_s0 = a_src[wn * 32 + cl],      a_d0 = a_dst[wn * 32 + cl];
  const float a_s1 = a_src[wn * 32 + 16 + cl], a_d1 = a_dst[wn * 32 + 16 + cl];
#pragma unroll
  for (int mi = 0; mi < 2; ++mi) {
    int rl0 = wm * 32 + mi * 16 + (lane >> 4) * 4;
#pragma unroll
    for (int j = 0; j < 4; ++j) {
      int rl = rl0 + j;
      int gr = bm + rl;
#pragma unroll
      for (int ni = 0; ni < 2; ++ni) {
        int gc = wn * 32 + ni * 16 + cl;
        if (gr < M) C[(size_t)gr * 64 + gc] = f2bf(acc[mi][ni][j]);
      }
      float ps = acc[mi][0][j] * a_s0 + acc[mi][1][j] * a_s1;
      float pd = acc[mi][0][j] * a_d0 + acc[mi][1][j] * a_d1;
#pragma unroll
      for (int off = 1; off < 16; off <<= 1) {
        ps += __shfl_xor(ps, off);
        pd += __shfl_xor(pd, off);
      }
      if (cl == 0) {
        red[wn][rl][0] = ps;
        red[wn][rl][1] = pd;
      }
    }
  }
  __syncthreads();
  if (tid < 128) {
    int gr = bm + tid;
    if (gr < M) {
      asrc[gr] = red[0][tid][0] + red[1][tid][0];
      adst[gr] = red[0][tid][1] + red[1][tid][1];
    }
  }
}

// ---------------- layer-2 aggregation: 8 edge slots x 8 lanes, batched ----------------
__global__ void k_agg2(const int* __restrict__ offs, const int* __restrict__ csr_src,
                       const unsigned short* __restrict__ h2b, const float* __restrict__ asrc,
                       const float* __restrict__ adst, const float* __restrict__ b2,
                       int n, float* __restrict__ out) {
  int wave = (blockIdx.x * blockDim.x + threadIdx.x) >> 6;
  int lane = threadIdx.x & 63;
  if (wave >= n) return;
  int wv = __builtin_amdgcn_readfirstlane(wave);
  float ad = adst[wv];
  int b = offs[wv], e2 = offs[wv + 1];
  const int es = lane >> 3;
  const int cg = lane & 7;
  float ssum = 0.f;
  float acc[8] = {};
  int i = b;
  for (; i + 15 < e2; i += 16) {
    int s0 = csr_src[i + es], s1 = csr_src[i + 8 + es];
    u16x8 r0 = *(const u16x8*)&h2b[(size_t)s0 * ODIM + cg * 8];
    u16x8 r1 = *(const u16x8*)&h2b[(size_t)s1 * ODIM + cg * 8];
    float a0 = asrc[s0], a1 = asrc[s1];
    float w0 = __expf(lrelu(a0 + ad));
    float w1 = __expf(lrelu(a1 + ad));
    ssum += w0 + w1;
#pragma unroll
    for (int j = 0; j < 8; ++j) acc[j] += w0 * bf2f(r0[j]) + w1 * bf2f(r1[j]);
  }
  for (; i < e2; i += 8) {
    int idx = i + es;
    bool act = idx < e2;
    int s = csr_src[act ? idx : e2 - 1];
    u16x8 r = *(const u16x8*)&h2b[(size_t)s * ODIM + cg * 8];
    float w = act ? __expf(lrelu(asrc[s] + ad)) : 0.f;
    ssum += w;
#pragma unroll
    for (int j = 0; j < 8; ++j) acc[j] += w * bf2f(r[j]);
  }
#pragma unroll
  for (int off = 8; off < 64; off <<= 1) {
    ssum += __shfl_xor(ssum, off);
#pragma unroll
    for (int j = 0; j < 8; ++j) acc[j] += __shfl_xor(acc[j], off);
  }
  if (lane < 8) {
    float r = 1.f / ssum;
    float4 bb0 = *(const float4*)&b2[cg * 8];
    float4 bb1 = *(const float4*)&b2[cg * 8 + 4];
    float4 o0, o1;
    o0.x = acc[0] * r + bb0.x; o0.y = acc[1] * r + bb0.y;
    o0.z = acc[2] * r + bb0.z; o0.w = acc[3] * r + bb0.w;
    o1.x = acc[4] * r + bb1.x; o1.y = acc[5] * r + bb1.y;
    o1.z = acc[6] * r + bb1.z; o1.w = acc[7] * r + bb1.w;
    *(float4*)&out[(size_t)wave * ODIM + cg * 8] = o0;
    *(float4*)&out[(size_t)wave * ODIM + cg * 8 + 4] = o1;
  }
}

extern "C" void kernel_launch(void* const* d_in, const int* in_sizes, int n_in,
                              void* d_out, int out_size, void* d_ws, size_t ws_size,
                              hipStream_t stream) {
  const float* x      = (const float*)d_in[0];
  const int* eidx     = (const int*)d_in[1];
  const float* W1     = (const float*)d_in[2];
  const float* asrc1w = (const float*)d_in[3];
  const float* adst1w = (const float*)d_in[4];
  const float* b1     = (const float*)d_in[5];
  const float* W2     = (const float*)d_in[6];
  const float* asrc2w = (const float*)d_in[7];
  const float* adst2w = (const float*)d_in[8];
  const float* b2     = (const float*)d_in[9];
  float* out = (float*)d_out;

  const int N = in_sizes[0] / D1;     // 50000
  const int E = in_sizes[1] / 2;      // 800000
  const int TE = E + N;
  const int* src = eidx;
  const int* dst = eidx + E;
  const int Mblk = (N + 127) / 128;   // 391
  const int Mpad = Mblk * 128;        // 50048
  const int nb_n = (N + 255) / 256;   // 196
  const int nb_te = (TE + 255) / 256;
  const int nb_sc = (TE + 511) / 512;
  const int cps = (N + 63) / 64;      // chunks per slice (782)

  // ---- workspace carve-up ----
  char* ws = (char*)d_ws;
  size_t off = 0;
  auto carve = [&](size_t bytes) -> char* {
    char* p = ws + off;
    off = (off + bytes + 255) & ~(size_t)255;
    return p;
  };
  unsigned short* helu = (unsigned short*)carve((size_t)Mpad * D1 * 2);   // 25.6 MB
  unsigned short* h1b  = (unsigned short*)carve((size_t)Mpad * D1 * 2);   // 25.6 MB
  unsigned short* h2b  = (unsigned short*)carve((size_t)N * ODIM * 2);    // 6.4 MB
  unsigned short* BT1  = (unsigned short*)carve((size_t)256 * 256 * 2);
  unsigned short* B2T2 = (unsigned short*)carve((size_t)64 * 256 * 2);
  float* asrc1 = (float*)carve((size_t)N * HEADS * 4);
  float* adst1 = (float*)carve((size_t)N * HEADS * 4);
  float* asrc2 = (float*)carve((size_t)N * 4);
  float* adst2 = (float*)carve((size_t)N * 4);
  // zero region: deg | tstate | ticket | sticket
  int* zr      = (int*)carve((size_t)(N + nb_n + 64) * 4);
  int* deg     = zr;
  int* tstate  = zr + N;
  int* ticket  = zr + N + nb_n;
  int* sticket = zr + N + nb_n + 1;
  int* offs    = (int*)carve((size_t)(N + 1) * 4);
  int* erank   = (int*)carve((size_t)TE * 4);
  int* csr_src = (int*)carve((size_t)TE * 4);

  // ---- CSR build ----
  hipMemsetAsync(zr, 0, (size_t)(N + nb_n + 16) * 4, stream);
  {
    const int HB = nb_te;
    const int PB = (65536 + 16384) / 256;
    k_hist_prep<<<HB + PB, 256, 0, stream>>>(dst, E, TE, deg, erank, W1, W2, BT1, B2T2, HB);
  }
  k_scan_lb<<<nb_n, 256, 0, stream>>>(deg, N, TE, offs, tstate, ticket);

  // ---- layer 1: GEMM + fused alpha1, overlapped with atomic-free scatter ----
  k_gemm1s<<<Mblk + nb_sc, 512, 0, stream>>>(x, BT1, asrc1w, adst1w, h1b, asrc1, adst1,
                                             N, Mblk, src, dst, E, TE, offs, erank, csr_src);

  // ---- layer-1 aggregation, XCD-sliced by head ----
  k_agg1<<<8 * cps, 256, 0, stream>>>(offs, csr_src, h1b, asrc1, adst1, b1,
                                      N, cps, sticket, helu);

  // ---- layer 2: GEMM + fused alpha2 ----
  k_gemm2<<<Mblk, 512, 0, stream>>>(helu, B2T2, asrc2w, adst2w, h2b, asrc2, adst2, N);
  k_agg2<<<(N + 3) / 4, 256, 0, stream>>>(offs, csr_src, h2b, asrc2, adst2, b2, N, out);
}

// Round 14
// 211.706 us; speedup vs baseline: 1.6633x; 1.6633x over previous
//
#include <hip/hip_runtime.h>
#include <hip/hip_bf16.h>

static constexpr int HEADS = 8;
static constexpr int D1 = 256;      // HEADS*HID
static constexpr int ODIM = 64;
static constexpr float NEG = 0.2f;

typedef __attribute__((ext_vector_type(8))) short bf16x8;
typedef __attribute__((ext_vector_type(8))) unsigned short u16x8;
typedef __attribute__((ext_vector_type(4))) float f32x4;

__device__ __forceinline__ float lrelu(float x) { return fmaxf(x, NEG * x); }
__device__ __forceinline__ float elu1(float x) { return x > 0.f ? x : expm1f(x); }

__device__ __forceinline__ unsigned short f2bf(float f) {
  unsigned u = __float_as_uint(f);
  unsigned r = (u + 0x7fffu + ((u >> 16) & 1u)) >> 16;
  return (unsigned short)r;
}
__device__ __forceinline__ float bf2f(unsigned short h) {
  return __uint_as_float((unsigned)h << 16);
}

__device__ __forceinline__ void gload_lds16(const void* g, void* l) {
  __builtin_amdgcn_global_load_lds(
      (const __attribute__((address_space(1))) void*)g,
      (__attribute__((address_space(3))) void*)l, 16, 0, 0);
}

// ---------------- hist (rank-capturing) + weight-prep (merged) ----------------
__global__ void k_hist_prep(const int* __restrict__ dst, int E, int TE,
                            int* __restrict__ deg, int* __restrict__ erank,
                            const float* __restrict__ W1, const float* __restrict__ W2,
                            unsigned short* __restrict__ BT1, unsigned short* __restrict__ B2T,
                            int HB) {
  int b = blockIdx.x;
  if (b < HB) {
    int i = b * 256 + threadIdx.x;
    if (i < TE) {
      int d = (i < E) ? __builtin_nontemporal_load(&dst[i]) : (i - E);
      int rk = atomicAdd(&deg[d], 1);   // rank within segment, fixes scatter order
      __builtin_nontemporal_store(rk, &erank[i]);
    }
  } else {
    int t = (b - HB) * 256 + threadIdx.x;
    if (t < 65536) {
      int k = t >> 8, nn = t & 255;
      BT1[nn * 256 + k] = f2bf(W1[t]);
    } else if (t < 65536 + 16384) {
      int t2 = t - 65536;
      int k = t2 >> 6, nn = t2 & 63;
      B2T[nn * 256 + k] = f2bf(W2[t2]);
    }
  }
}

// ---------------- single-launch exclusive scan (decoupled lookback) ----------------
__global__ void k_scan_lb(const int* __restrict__ deg, int n, int TE,
                          int* __restrict__ offs,
                          int* __restrict__ tstate, int* __restrict__ ticket) {
  __shared__ int sm[256];
  __shared__ int sh[2];  // [0]=tile, [1]=base
  if (threadIdx.x == 0) sh[0] = atomicAdd(ticket, 1);
  __syncthreads();
  const int tile = sh[0];
  int i = tile * 256 + threadIdx.x;
  int v = (i < n) ? deg[i] : 0;
  sm[threadIdx.x] = v;
  __syncthreads();
  for (int off = 1; off < 256; off <<= 1) {
    int t = (threadIdx.x >= off) ? sm[threadIdx.x - off] : 0;
    __syncthreads();
    sm[threadIdx.x] += t;
    __syncthreads();
  }
  const int total = sm[255];
  if (threadIdx.x == 0) {
    if (tile == 0) {
      __hip_atomic_store(&tstate[0], (2 << 24) | total, __ATOMIC_RELEASE,
                         __HIP_MEMORY_SCOPE_AGENT);
      sh[1] = 0;
    } else {
      __hip_atomic_store(&tstate[tile], (1 << 24) | total, __ATOMIC_RELEASE,
                         __HIP_MEMORY_SCOPE_AGENT);
    }
  }
  __syncthreads();
  if (tile != 0) {
    if (threadIdx.x < 64) {
      const int lane = threadIdx.x;
      int running = 0;
      int wstart = tile - 1;
      for (;;) {
        int idx = wstart - lane;
        int st = (idx >= 0)
                     ? __hip_atomic_load(&tstate[idx], __ATOMIC_ACQUIRE,
                                         __HIP_MEMORY_SCOPE_AGENT)
                     : (2 << 24);
        if (__ballot(st == 0)) continue;
        unsigned long long pref = __ballot((st >> 24) == 2);
        int contrib;
        if (pref) {
          int flane = (int)__ffsll(pref) - 1;
          contrib = (lane <= flane) ? (st & 0xFFFFFF) : 0;
        } else {
          contrib = st & 0xFFFFFF;
        }
#pragma unroll
        for (int off2 = 1; off2 < 64; off2 <<= 1) contrib += __shfl_xor(contrib, off2);
        running += contrib;
        if (pref) break;
        wstart -= 64;
      }
      if (lane == 0) {
        sh[1] = running;
        __hip_atomic_store(&tstate[tile], (2 << 24) | (running + total),
                           __ATOMIC_RELEASE, __HIP_MEMORY_SCOPE_AGENT);
      }
    }
    __syncthreads();
  }
  const int base = sh[1];
  if (i < n) offs[i] = base + sm[threadIdx.x] - v;
  if (i == 0) offs[n] = TE;
}

// ---------------- GEMM1 (1-term bf16, BN=256, x-prefetch) + fused alpha1 ∥ atomic-free scatter ----
__global__ __launch_bounds__(512) void k_gemm1s(
    const float* __restrict__ X,            // [M][256]
    const unsigned short* __restrict__ BT,  // BT1 [256n][256k] (hi)
    const float* __restrict__ a_src, const float* __restrict__ a_dst,
    unsigned short* __restrict__ h1b,       // [Mpad][256]
    float* __restrict__ asrc, float* __restrict__ adst,
    int M, int Mblk,
    const int* __restrict__ src, const int* __restrict__ dst, int E, int TE,
    const int* __restrict__ offs, const int* __restrict__ erank,
    int* __restrict__ csr_src) {
  __shared__ __align__(128) char As[16384];   // [128r][128B] XOR-swizzled
  __shared__ __align__(128) char Bs[32768];   // [256c][128B] XOR-swizzled
  if (blockIdx.x >= Mblk) {
    // ---- scatter part: pure writes, no atomics ----
    int i = (blockIdx.x - Mblk) * 512 + threadIdx.x;
    if (i < TE) {
      int s, d;
      if (i < E) {
        s = __builtin_nontemporal_load(&src[i]);
        d = __builtin_nontemporal_load(&dst[i]);
      } else { s = i - E; d = i - E; }
      int rk = __builtin_nontemporal_load(&erank[i]);
      __builtin_nontemporal_store(s, &csr_src[offs[d] + rk]);
    }
    return;
  }
  const int tid = threadIdx.x;
  const int lane = tid & 63;
  const int wid = tid >> 6;
  const int bm = blockIdx.x * 128;
  const int wm = wid >> 2, wn = wid & 3;      // wave tile 64x64
  f32x4 acc[4][4] = {};
  float4 xv[2][2];
  auto loadX = [&](int kb) {
#pragma unroll
    for (int q = 0; q < 2; ++q) {
      int c = q * 512 + tid;
      int r = c >> 3, kc = c & 7;
      int gr = bm + r;
      xv[q][0] = make_float4(0.f, 0.f, 0.f, 0.f);
      xv[q][1] = xv[q][0];
      if (gr < M) {
        xv[q][0] = *(const float4*)&X[(size_t)gr * 256 + kb + kc * 8];
        xv[q][1] = *(const float4*)&X[(size_t)gr * 256 + kb + kc * 8 + 4];
      }
    }
  };
  loadX(0);
  for (int kb = 0; kb < 256; kb += 64) {
#pragma unroll
    for (int q = 0; q < 2; ++q) {
      int c = q * 512 + tid;
      int r = c >> 3, kc = c & 7;
      float vv[8] = {xv[q][0].x, xv[q][0].y, xv[q][0].z, xv[q][0].w,
                     xv[q][1].x, xv[q][1].y, xv[q][1].z, xv[q][1].w};
      u16x8 hv;
#pragma unroll
      for (int j = 0; j < 8; ++j) hv[j] = f2bf(vv[j]);
      *(u16x8*)(As + r * 128 + ((kc * 16) ^ ((r & 7) << 4))) = hv;
    }
#pragma unroll
    for (int q = 0; q < 4; ++q) {
      int c = q * 512 + tid;                   // chunk 0..2047
      int col = c >> 3;                        // 0..255
      int b = ((c & 7) * 16) ^ ((col & 7) << 4);
      gload_lds16(BT + (size_t)col * 256 + kb + (b >> 1),
                  Bs + (size_t)(q * 512 + (tid & ~63)) * 16);
    }
    __syncthreads();
    if (kb + 64 < 256) loadX(kb + 64);  // prefetch next x under MFMA
#pragma unroll
    for (int ks = 0; ks < 2; ++ks) {
      bf16x8 af[4], bfr[4];
      int bb = ks * 64 + (lane >> 4) * 16;
#pragma unroll
      for (int mi = 0; mi < 4; ++mi) {
        int row = wm * 64 + mi * 16 + (lane & 15);
        af[mi] = *(const bf16x8*)(As + row * 128 + (bb ^ ((row & 7) << 4)));
      }
#pragma unroll
      for (int ni = 0; ni < 4; ++ni) {
        int col = wn * 64 + ni * 16 + (lane & 15);
        bfr[ni] = *(const bf16x8*)(Bs + col * 128 + (bb ^ ((col & 7) << 4)));
      }
#pragma unroll
      for (int mi = 0; mi < 4; ++mi)
#pragma unroll
        for (int ni = 0; ni < 4; ++ni)
          acc[mi][ni] = __builtin_amdgcn_mfma_f32_16x16x32_bf16(af[mi], bfr[ni],
                                                                acc[mi][ni], 0, 0, 0);
    }
    __syncthreads();
  }
  // ---- epilogue: h1b write + fused alpha1 (heads 2wn, 2wn+1) ----
  const int h0 = 2 * wn, h1h = 2 * wn + 1;
  const int cl = lane & 15;
  const float as0 = a_src[h0 * 32 + cl],      ad0 = a_dst[h0 * 32 + cl];
  const float as1 = a_src[h0 * 32 + 16 + cl], ad1 = a_dst[h0 * 32 + 16 + cl];
  const float as2 = a_src[h1h * 32 + cl],      ad2 = a_dst[h1h * 32 + cl];
  const float as3 = a_src[h1h * 32 + 16 + cl], ad3 = a_dst[h1h * 32 + 16 + cl];
#pragma unroll
  for (int mi = 0; mi < 4; ++mi) {
    int gr0 = bm + wm * 64 + mi * 16 + (lane >> 4) * 4;
#pragma unroll
    for (int j = 0; j < 4; ++j) {
      int gr = gr0 + j;
#pragma unroll
      for (int ni = 0; ni < 4; ++ni) {
        int gc = wn * 64 + ni * 16 + cl;
        if (gr < M) h1b[(size_t)gr * 256 + gc] = f2bf(acc[mi][ni][j]);
      }
      float ps0 = acc[mi][0][j] * as0 + acc[mi][1][j] * as1;
      float pd0 = acc[mi][0][j] * ad0 + acc[mi][1][j] * ad1;
      float ps1 = acc[mi][2][j] * as2 + acc[mi][3][j] * as3;
      float pd1 = acc[mi][2][j] * ad2 + acc[mi][3][j] * ad3;
#pragma unroll
      for (int off = 1; off < 16; off <<= 1) {
        ps0 += __shfl_xor(ps0, off);
        pd0 += __shfl_xor(pd0, off);
        ps1 += __shfl_xor(ps1, off);
        pd1 += __shfl_xor(pd1, off);
      }
      if (cl == 0 && gr < M) {
        asrc[gr * 8 + h0] = ps0;
        adst[gr * 8 + h0] = pd0;
        asrc[gr * 8 + h1h] = ps1;
        adst[gr * 8 + h1h] = pd1;
      }
    }
  }
}

// ---------------- layer-1 aggregation: 2 edge slots x 32 lanes, batched phases ----------------
__global__ void k_agg1(const int* __restrict__ offs, const int* __restrict__ csr_src,
                       const unsigned short* __restrict__ h1b, const float* __restrict__ asrc,
                       const float* __restrict__ adst, const float* __restrict__ b1,
                       int n, unsigned short* __restrict__ helu) {
  int wave = (blockIdx.x * blockDim.x + threadIdx.x) >> 6;
  int lane = threadIdx.x & 63;
  if (wave >= n) return;
  int wv = __builtin_amdgcn_readfirstlane(wave);
  const int es = lane >> 5;   // edge slot 0..1
  const int cg = lane & 31;   // channel octet
  const int hh = cg >> 2;     // head
  float ad = adst[wv * 8 + hh];
  int b = offs[wv], e2 = offs[wv + 1];
  float ssum = 0.f;
  float acc[8] = {};
  int i = b;
  for (; i + 7 < e2; i += 8) {
    int s[4];
#pragma unroll
    for (int u = 0; u < 4; ++u) s[u] = csr_src[i + 2 * u + es];
    u16x8 r[4];
    float as_[4];
#pragma unroll
    for (int u = 0; u < 4; ++u) {
      r[u] = *(const u16x8*)&h1b[(size_t)s[u] * D1 + cg * 8];
      as_[u] = asrc[s[u] * 8 + hh];
    }
#pragma unroll
    for (int u = 0; u < 4; ++u) {
      float w = __expf(lrelu(as_[u] + ad));
      ssum += w;
#pragma unroll
      for (int j = 0; j < 8; ++j) acc[j] += w * bf2f(r[u][j]);
    }
  }
  for (; i < e2; i += 2) {
    int idx = i + es;
    bool act = idx < e2;
    int s = csr_src[act ? idx : e2 - 1];
    u16x8 r = *(const u16x8*)&h1b[(size_t)s * D1 + cg * 8];
    float w = act ? __expf(lrelu(asrc[s * 8 + hh] + ad)) : 0.f;
    ssum += w;
#pragma unroll
    for (int j = 0; j < 8; ++j) acc[j] += w * bf2f(r[j]);
  }
  ssum += __shfl_xor(ssum, 32);
#pragma unroll
  for (int j = 0; j < 8; ++j) acc[j] += __shfl_xor(acc[j], 32);
  if (lane < 32) {
    float rr = 1.f / ssum;
    float4 bb0 = *(const float4*)&b1[cg * 8];
    float4 bb1 = *(const float4*)&b1[cg * 8 + 4];
    float bbv[8] = {bb0.x, bb0.y, bb0.z, bb0.w, bb1.x, bb1.y, bb1.z, bb1.w};
    u16x8 o;
#pragma unroll
    for (int j = 0; j < 8; ++j) o[j] = f2bf(elu1(acc[j] * rr + bbv[j]));
    *(u16x8*)&helu[(size_t)wave * D1 + cg * 8] = o;
  }
}

// ---------------- GEMM2 (1-term bf16, K=256) + fused alpha2 ----------------
__global__ __launch_bounds__(512) void k_gemm2(
    const unsigned short* __restrict__ A,    // helu [Mpad][256] bf16
    const unsigned short* __restrict__ B2T,  // [64][256] (hi)
    const float* __restrict__ a_src, const float* __restrict__ a_dst,
    unsigned short* __restrict__ C,          // h2b [M][64]
    float* __restrict__ asrc, float* __restrict__ adst,
    int M) {
  __shared__ __align__(128) char As[16384];  // [128r][128B]
  __shared__ __align__(128) char Bs[8192];   // [64c][128B]
  __shared__ float red[2][128][2];           // [wn][row][ps/pd]
  const int tid = threadIdx.x;
  const int lane = tid & 63;
  const int wid = tid >> 6;
  const int bm = blockIdx.x * 128;
  const int wm = wid >> 1, wn = wid & 1;     // wave tile 32x32
  f32x4 acc[2][2] = {};
  for (int kb = 0; kb < 256; kb += 64) {
#pragma unroll
    for (int q = 0; q < 2; ++q) {
      int c = q * 512 + tid;
      int r = c >> 3;
      int b = ((c & 7) * 16) ^ ((r & 7) << 4);
      gload_lds16(A + (size_t)(bm + r) * 256 + kb + (b >> 1),
                  As + (size_t)(q * 512 + (tid & ~63)) * 16);
    }
    {
      int c = tid;  // 512 chunks
      int col = c >> 3;
      int b = ((c & 7) * 16) ^ ((col & 7) << 4);
      gload_lds16(B2T + (size_t)col * 256 + kb + (b >> 1),
                  Bs + (size_t)(tid & ~63) * 16);
    }
    __syncthreads();
#pragma unroll
    for (int ks = 0; ks < 2; ++ks) {
      bf16x8 af[2], bfr[2];
      int bb = ks * 64 + (lane >> 4) * 16;
#pragma unroll
      for (int mi = 0; mi < 2; ++mi) {
        int row = wm * 32 + mi * 16 + (lane & 15);
        af[mi] = *(const bf16x8*)(As + row * 128 + (bb ^ ((row & 7) << 4)));
      }
#pragma unroll
      for (int ni = 0; ni < 2; ++ni) {
        int col = wn * 32 + ni * 16 + (lane & 15);
        bfr[ni] = *(const bf16x8*)(Bs + col * 128 + (bb ^ ((col & 7) << 4)));
      }
#pragma unroll
      for (int mi = 0; mi < 2; ++mi)
#pragma unroll
        for (int ni = 0; ni < 2; ++ni)
          acc[mi][ni] = __builtin_amdgcn_mfma_f32_16x16x32_bf16(af[mi], bfr[ni],
                                                                acc[mi][ni], 0, 0, 0);
    }
    __syncthreads();
  }
  const int cl = lane & 15;
  const float a_s0 = a_src[wn * 32 + cl],      a_d0 = a_dst[wn * 32 + cl];
  const float a_s1 = a_src[wn * 32 + 16 + cl], a_d1 = a_dst[wn * 32 + 16 + cl];
#pragma unroll
  for (int mi = 0; mi < 2; ++mi) {
    int rl0 = wm * 32 + mi * 16 + (lane >> 4) * 4;
#pragma unroll
    for (int j = 0; j < 4; ++j) {
      int rl = rl0 + j;
      int gr = bm + rl;
#pragma unroll
      for (int ni = 0; ni < 2; ++ni) {
        int gc = wn * 32 + ni * 16 + cl;
        if (gr < M) C[(size_t)gr * 64 + gc] = f2bf(acc[mi][ni][j]);
      }
      float ps = acc[mi][0][j] * a_s0 + acc[mi][1][j] * a_s1;
      float pd = acc[mi][0][j] * a_d0 + acc[mi][1][j] * a_d1;
#pragma unroll
      for (int off = 1; off < 16; off <<= 1) {
        ps += __shfl_xor(ps, off);
        pd += __shfl_xor(pd, off);
      }
      if (cl == 0) {
        red[wn][rl][0] = ps;
        red[wn][rl][1] = pd;
      }
    }
  }
  __syncthreads();
  if (tid < 128) {
    int gr = bm + tid;
    if (gr < M) {
      asrc[gr] = red[0][tid][0] + red[1][tid][0];
      adst[gr] = red[0][tid][1] + red[1][tid][1];
    }
  }
}

// ---------------- layer-2 aggregation: 8 edge slots x 8 lanes, batched ----------------
__global__ void k_agg2(const int* __restrict__ offs, const int* __restrict__ csr_src,
                       const unsigned short* __restrict__ h2b, const float* __restrict__ asrc,
                       const float* __restrict__ adst, const float* __restrict__ b2,
                       int n, float* __restrict__ out) {
  int wave = (blockIdx.x * blockDim.x + threadIdx.x) >> 6;
  int lane = threadIdx.x & 63;
  if (wave >= n) return;
  int wv = __builtin_amdgcn_readfirstlane(wave);
  float ad = adst[wv];
  int b = offs[wv], e2 = offs[wv + 1];
  const int es = lane >> 3;  // edge slot 0..7
  const int cg = lane & 7;   // channel octet 0..7
  float ssum = 0.f;
  float acc[8] = {};
  int i = b;
  for (; i + 15 < e2; i += 16) {
    int s0 = csr_src[i + es], s1 = csr_src[i + 8 + es];
    u16x8 r0 = *(const u16x8*)&h2b[(size_t)s0 * ODIM + cg * 8];
    u16x8 r1 = *(const u16x8*)&h2b[(size_t)s1 * ODIM + cg * 8];
    float a0 = asrc[s0], a1 = asrc[s1];
    float w0 = __expf(lrelu(a0 + ad));
    float w1 = __expf(lrelu(a1 + ad));
    ssum += w0 + w1;
#pragma unroll
    for (int j = 0; j < 8; ++j) acc[j] += w0 * bf2f(r0[j]) + w1 * bf2f(r1[j]);
  }
  for (; i < e2; i += 8) {
    int idx = i + es;
    bool act = idx < e2;
    int s = csr_src[act ? idx : e2 - 1];
    u16x8 r = *(const u16x8*)&h2b[(size_t)s * ODIM + cg * 8];
    float w = act ? __expf(lrelu(asrc[s] + ad)) : 0.f;
    ssum += w;
#pragma unroll
    for (int j = 0; j < 8; ++j) acc[j] += w * bf2f(r[j]);
  }
#pragma unroll
  for (int off = 8; off < 64; off <<= 1) {
    ssum += __shfl_xor(ssum, off);
#pragma unroll
    for (int j = 0; j < 8; ++j) acc[j] += __shfl_xor(acc[j], off);
  }
  if (lane < 8) {
    float r = 1.f / ssum;
    float4 bb0 = *(const float4*)&b2[cg * 8];
    float4 bb1 = *(const float4*)&b2[cg * 8 + 4];
    float4 o0, o1;
    o0.x = acc[0] * r + bb0.x; o0.y = acc[1] * r + bb0.y;
    o0.z = acc[2] * r + bb0.z; o0.w = acc[3] * r + bb0.w;
    o1.x = acc[4] * r + bb1.x; o1.y = acc[5] * r + bb1.y;
    o1.z = acc[6] * r + bb1.z; o1.w = acc[7] * r + bb1.w;
    *(float4*)&out[(size_t)wave * ODIM + cg * 8] = o0;
    *(float4*)&out[(size_t)wave * ODIM + cg * 8 + 4] = o1;
  }
}

extern "C" void kernel_launch(void* const* d_in, const int* in_sizes, int n_in,
                              void* d_out, int out_size, void* d_ws, size_t ws_size,
                              hipStream_t stream) {
  const float* x      = (const float*)d_in[0];
  const int* eidx     = (const int*)d_in[1];
  const float* W1     = (const float*)d_in[2];
  const float* asrc1w = (const float*)d_in[3];
  const float* adst1w = (const float*)d_in[4];
  const float* b1     = (const float*)d_in[5];
  const float* W2     = (const float*)d_in[6];
  const float* asrc2w = (const float*)d_in[7];
  const float* adst2w = (const float*)d_in[8];
  const float* b2     = (const float*)d_in[9];
  float* out = (float*)d_out;

  const int N = in_sizes[0] / D1;     // 50000
  const int E = in_sizes[1] / 2;      // 800000
  const int TE = E + N;
  const int* src = eidx;
  const int* dst = eidx + E;
  const int Mblk = (N + 127) / 128;   // 391
  const int Mpad = Mblk * 128;        // 50048
  const int nb_n = (N + 255) / 256;   // 196
  const int nb_te = (TE + 255) / 256;
  const int nb_sc = (TE + 511) / 512; // scatter blocks (512 thr)

  // ---- workspace carve-up ----
  char* ws = (char*)d_ws;
  size_t off = 0;
  auto carve = [&](size_t bytes) -> char* {
    char* p = ws + off;
    off = (off + bytes + 255) & ~(size_t)255;
    return p;
  };
  unsigned short* helu = (unsigned short*)carve((size_t)Mpad * D1 * 2);   // 25.6 MB
  unsigned short* h1b  = (unsigned short*)carve((size_t)Mpad * D1 * 2);   // 25.6 MB
  unsigned short* h2b  = (unsigned short*)carve((size_t)N * ODIM * 2);    // 6.4 MB
  unsigned short* BT1  = (unsigned short*)carve((size_t)256 * 256 * 2);
  unsigned short* B2T2 = (unsigned short*)carve((size_t)64 * 256 * 2);
  float* asrc1 = (float*)carve((size_t)N * HEADS * 4);
  float* adst1 = (float*)carve((size_t)N * HEADS * 4);
  float* asrc2 = (float*)carve((size_t)N * 4);
  float* adst2 = (float*)carve((size_t)N * 4);
  // zero region: deg | tstate | ticket  (single memset)
  int* zr      = (int*)carve((size_t)(N + nb_n + 64) * 4);
  int* deg     = zr;
  int* tstate  = zr + N;
  int* ticket  = zr + N + nb_n;
  int* offs    = (int*)carve((size_t)(N + 1) * 4);
  int* erank   = (int*)carve((size_t)TE * 4);
  int* csr_src = (int*)carve((size_t)TE * 4);

  // ---- CSR build (hist captures ranks; scatter is atomic-free, overlapped with gemm1) ----
  hipMemsetAsync(zr, 0, (size_t)(N + nb_n + 1) * 4, stream);
  {
    const int HB = nb_te;
    const int PB = (65536 + 16384) / 256;  // 320 prep blocks
    k_hist_prep<<<HB + PB, 256, 0, stream>>>(dst, E, TE, deg, erank, W1, W2, BT1, B2T2, HB);
  }
  k_scan_lb<<<nb_n, 256, 0, stream>>>(deg, N, TE, offs, tstate, ticket);

  // ---- layer 1: GEMM + fused alpha1, overlapped with atomic-free scatter ----
  k_gemm1s<<<Mblk + nb_sc, 512, 0, stream>>>(x, BT1, asrc1w, adst1w, h1b, asrc1, adst1,
                                             N, Mblk, src, dst, E, TE, offs, erank, csr_src);
  k_agg1<<<(N + 3) / 4, 256, 0, stream>>>(offs, csr_src, h1b, asrc1, adst1, b1, N, helu);

  // ---- layer 2: GEMM + fused alpha2 ----
  k_gemm2<<<Mblk, 512, 0, stream>>>(helu, B2T2, asrc2w, adst2w, h2b, asrc2, adst2, N);
  k_agg2<<<(N + 3) / 4, 256, 0, stream>>>(offs, csr_src, h2b, asrc2, adst2, b2, N, out);
}